// Round 6
// baseline (257.814 us; speedup 1.0000x reference)
//
#include <hip/hip_runtime.h>

using bf16x8 = __attribute__((ext_vector_type(8))) short;
using f32x4  = __attribute__((ext_vector_type(4))) float;

constexpr int Bb = 8, Nn = 8192, Mm = 2048, C1 = 128, C2 = 256, Hh = 256, K1 = 384;
constexpr int KT1 = K1 / 32;   // 12 k-tiles for GEMM1
constexpr int KT2 = Hh / 32;   // 8 k-tiles for GEMM2
constexpr int RT = Hh / 16;    // 16 row-tiles
constexpr int NQ = 4;          // candidate-set split for three_nn
constexpr int MQ = Mm / NQ;    // 512 candidates per quarter

// block-role ranges for the combined prep+nn kernel
constexpr int TR_BLOCKS = 4096;                                  // kf transpose
constexpr int WP_BLOCKS = (KT1 * RT * 64 + KT2 * RT * 64) / 256; // 80, W prep
constexpr int NN_BASE   = TR_BLOCKS + WP_BLOCKS;                 // 4176
constexpr int NN_BLOCKS = Bb * 32 * NQ;                          // 1024

__device__ __forceinline__ short f2bf(float x) {  // RNE float->bf16
  union { float f; unsigned u; } v; v.f = x;
  unsigned r = v.u + 0x7fff + ((v.u >> 16) & 1);
  return (short)(r >> 16);
}

// packed RNE float2 -> 2x bf16 in one dword (hw instr when available)
__device__ __forceinline__ unsigned pk2bf(float a, float b) {
#if defined(__has_builtin) && __has_builtin(__builtin_amdgcn_cvt_pk_bf16_f32)
  typedef __attribute__((ext_vector_type(2))) __bf16 bf2_t;
  bf2_t r = __builtin_amdgcn_cvt_pk_bf16_f32(a, b);
  union { bf2_t v; unsigned u; } cvt; cvt.v = r;
  return cvt.u;
#else
  return (unsigned)(unsigned short)f2bf(a) | ((unsigned)(unsigned short)f2bf(b) << 16);
#endif
}

// stable 2-list merge of sorted triples; ties prefer list a (lower global idx)
__device__ __forceinline__ void merge3(float a0, float a1, float a2, int A0, int A1, int A2,
                                       float b0, float b1, float b2, int B0, int B1, int B2,
                                       float& m0, float& m1, float& m2,
                                       int& j0, int& j1, int& j2) {
  bool ta = a0 <= b0;
  m0 = ta ? a0 : b0; j0 = ta ? A0 : B0;
  float na0 = ta ? a1 : a0, na1 = ta ? a2 : a1;
  int   nA0 = ta ? A1 : A0, nA1 = ta ? A2 : A1;
  float nb0 = ta ? b0 : b1, nb1 = ta ? b1 : b2;
  int   nB0 = ta ? B0 : B1, nB1 = ta ? B1 : B2;
  ta = na0 <= nb0;
  m1 = ta ? na0 : nb0; j1 = ta ? nA0 : nB0;
  float ma0 = ta ? na1 : na0; int mA0 = ta ? nA1 : nA0;
  float mb0 = ta ? nb0 : nb1; int mB0 = ta ? nB0 : nB1;
  ta = ma0 <= mb0;
  m2 = ta ? ma0 : mb0; j2 = ta ? mA0 : mB0;
}

// ------------- combined: kf transpose | W frag prep | three_nn quarters -------------
// Roles by blockIdx.x range; no cross-role data dependency inside the kernel.
// nn role is the R4 LDS-staged quarter scan (known-good 70 us; R5's scalar-load
// variant regressed to latency-bound 107 us — do not reintroduce).
__global__ __launch_bounds__(256) void prep_nn_k(const float* __restrict__ kf,
                                                 float* __restrict__ kfT,
                                                 const float* __restrict__ W1,
                                                 const float* __restrict__ W2,
                                                 short* __restrict__ W1f,
                                                 short* __restrict__ W2f,
                                                 const float* __restrict__ unknown,
                                                 const float* __restrict__ known,
                                                 float* __restrict__ pd,
                                                 int* __restrict__ pi) {
  __shared__ float smem[1536];  // transpose tile (1056 f) or nn kx/ky/kz (1536 f)
  int bid = blockIdx.x, tid = threadIdx.x;

  if (bid < TR_BLOCKS) {  // ---- transpose role: (B,C2,Mm) -> (B,Mm,C2)
    float (*tile)[33] = reinterpret_cast<float(*)[33]>(smem);
    int cx = bid & 63, ry = (bid >> 6) & 7, z = bid >> 9;
    const int R = C2, C = Mm;
    const float* src = kf + (size_t)z * R * C;
    float* dst = kfT + (size_t)z * R * C;
    int c0 = cx * 32, r0 = ry * 32;
    int tx = tid & 31, ty = tid >> 5;
#pragma unroll
    for (int rr = ty; rr < 32; rr += 8) tile[rr][tx] = src[(size_t)(r0 + rr) * C + c0 + tx];
    __syncthreads();
#pragma unroll
    for (int cc = ty; cc < 32; cc += 8) dst[(size_t)(c0 + cc) * R + r0 + tx] = tile[tx][cc];
    return;
  }

  if (bid < NN_BASE) {  // ---- W-prep role: A-frag planes (lane: A[m=lane&15][k0..k0+7])
    int id = (bid - TR_BLOCKS) * 256 + tid;
    const int n1 = KT1 * RT * 64;
    const int n2 = KT2 * RT * 64;
    if (id < n1) {
      int lane = id & 63, t = id >> 6;
      int kt = t / RT, rt = t % RT;
      int m = rt * 16 + (lane & 15), k0 = kt * 32 + (lane >> 4) * 8;
      bf16x8 f;
#pragma unroll
      for (int j = 0; j < 8; ++j) f[j] = f2bf(W1[(size_t)m * K1 + k0 + j]);
      *(bf16x8*)(W1f + (size_t)id * 8) = f;
    } else if (id < n1 + n2) {
      int id2 = id - n1;
      int lane = id2 & 63, t = id2 >> 6;
      int kt = t / RT, rt = t % RT;
      int m = rt * 16 + (lane & 15), k0 = kt * 32 + (lane >> 4) * 8;
      bf16x8 f;
#pragma unroll
      for (int j = 0; j < 8; ++j) f[j] = f2bf(W2[(size_t)m * Hh + k0 + j]);
      *(bf16x8*)(W2f + (size_t)id2 * 8) = f;
    }
    return;
  }

  // ---- three_nn role: quarter scan over LDS-staged candidates (R4 code)
  {
    float* kx = smem;
    float* ky = smem + MQ;
    float* kz = smem + 2 * MQ;
    int bidn = bid - NN_BASE;
    int b = bidn >> 7, rem = bidn & 127;
    int q = rem & 3, nblk = rem >> 2;
    int n = nblk * 256 + tid;
    const float* kb = known + ((size_t)b * Mm + q * MQ) * 3;
    for (int p = tid; p < MQ; p += 256) {
      kx[p] = kb[3 * p]; ky[p] = kb[3 * p + 1]; kz[p] = kb[3 * p + 2];
    }
    __syncthreads();

    size_t ui = ((size_t)b * Nn + n) * 3;
    float ux = unknown[ui], uy = unknown[ui + 1], uz = unknown[ui + 2];
    float d0 = 1e30f, d1 = 1e30f, d2 = 1e30f;
    int i0 = 0, i1 = 0, i2 = 0;
    int gbase = q * MQ;

#define NN_STEP(xx, yy, zz, qq)                                         \
  {                                                                     \
    float dx = ux - (xx), dy = uy - (yy), dz = uz - (zz);               \
    float dd = dx * dx + dy * dy + dz * dz;                             \
    if (__any(dd < d2)) {  /* wave-uniform skip of the insert chain */  \
      int jm = gbase + jb + (qq);                                       \
      bool c0 = dd < d0, c1 = dd < d1, c2 = dd < d2;                    \
      d2 = c1 ? d1 : (c2 ? dd : d2); i2 = c1 ? i1 : (c2 ? jm : i2);     \
      d1 = c0 ? d0 : (c1 ? dd : d1); i1 = c0 ? i0 : (c1 ? jm : i1);     \
      d0 = c0 ? dd : d0;             i0 = c0 ? jm : i0;                 \
    }                                                                   \
  }

    for (int jb = 0; jb < MQ; jb += 4) {
      float4 xs = *(const float4*)&kx[jb];
      float4 ys = *(const float4*)&ky[jb];
      float4 zs = *(const float4*)&kz[jb];
      NN_STEP(xs.x, ys.x, zs.x, 0)
      NN_STEP(xs.y, ys.y, zs.y, 1)
      NN_STEP(xs.z, ys.z, zs.z, 2)
      NN_STEP(xs.w, ys.w, zs.w, 3)
    }
#undef NN_STEP

    size_t o = (((size_t)b * Nn + n) * NQ + q) * 3;
    pd[o] = d0; pd[o + 1] = d1; pd[o + 2] = d2;
    pi[o] = i0; pi[o + 1] = i1; pi[o + 2] = i2;
  }
}

// ------------- fused: 4-way merge -> gather+concat -> MLP1 -> MLP2 -> out -------------
// block = 256 thr (4 waves), 64 cols x 256 rows. grid = 8*128 = 1024.
// LDS: 48KB total — Hs ALIASES the head of Fs (barrier between K-loop1 reads and
// Hs writes makes this safe) -> 3 blocks/CU (was 2 at 80KB).
__global__ __launch_bounds__(256) void fused_gemm_k(
    const float* __restrict__ uf, const float* __restrict__ kfT,
    const short* __restrict__ W1f, const float* __restrict__ b1,
    const short* __restrict__ W2f, const float* __restrict__ b2,
    const float* __restrict__ pd, const int* __restrict__ pi,
    float* __restrict__ out) {
  __shared__ short Fs[KT1 * 4 * 64 * 8];  // B-frags of F  [kt][ntl][lane][j]; head reused as Hs
  short* Hs = Fs;                         // B-frags of h  [ktg][ntl][lane][j] (16384 shorts)
  int bid = blockIdx.x;
  int b = bid >> 7, bt = bid & 127;  // n0 = bt*64
  int tid = threadIdx.x, lane = tid & 63, wv = tid >> 6;
  int quad = lane >> 4, col = lane & 15;

  // ---- Phase A: in-register 4-way NN merge, then gather+concat F in B-frag layout
  {
    int n = bt * 64 + wv * 16 + col;
    size_t pbase = (size_t)(b * Nn + n) * (NQ * 3);
    float4 da = *(const float4*)&pd[pbase];
    float4 db = *(const float4*)&pd[pbase + 4];
    float4 dc = *(const float4*)&pd[pbase + 8];
    int4 ia = *(const int4*)&pi[pbase];
    int4 ib = *(const int4*)&pi[pbase + 4];
    int4 ic = *(const int4*)&pi[pbase + 8];
    float t0, t1, t2, u0, u1, u2, m0, m1, m2;
    int T0, T1, T2, U0, U1, U2, g0, g1, g2;
    merge3(da.x, da.y, da.z, ia.x, ia.y, ia.z,
           da.w, db.x, db.y, ia.w, ib.x, ib.y, t0, t1, t2, T0, T1, T2);
    merge3(db.z, db.w, dc.x, ib.z, ib.w, ic.x,
           dc.y, dc.z, dc.w, ic.y, ic.z, ic.w, u0, u1, u2, U0, U1, U2);
    merge3(t0, t1, t2, T0, T1, T2, u0, u1, u2, U0, U1, U2,
           m0, m1, m2, g0, g1, g2);
    float s0 = sqrtf(m0), s1 = sqrtf(m1), s2 = sqrtf(m2);
    float r0 = 1.f / (s0 + 1e-8f), r1 = 1.f / (s1 + 1e-8f), r2 = 1.f / (s2 + 1e-8f);
    float rs = 1.f / (r0 + r1 + r2);
    float w0 = r0 * rs, w1 = r1 * rs, w2 = r2 * rs;

    const float* kfb = kfT + (size_t)b * Mm * C2;
#pragma unroll 4
    for (int kt = 0; kt < 8; ++kt) {  // interpolated region (C2 channels)
      int c0 = kt * 32 + quad * 8;
      float4 p0a = *(const float4*)&kfb[(size_t)g0 * C2 + c0];
      float4 p0b = *(const float4*)&kfb[(size_t)g0 * C2 + c0 + 4];
      float4 p1a = *(const float4*)&kfb[(size_t)g1 * C2 + c0];
      float4 p1b = *(const float4*)&kfb[(size_t)g1 * C2 + c0 + 4];
      float4 p2a = *(const float4*)&kfb[(size_t)g2 * C2 + c0];
      float4 p2b = *(const float4*)&kfb[(size_t)g2 * C2 + c0 + 4];
      float e0 = w0 * p0a.x + w1 * p1a.x + w2 * p2a.x;
      float e1 = w0 * p0a.y + w1 * p1a.y + w2 * p2a.y;
      float e2 = w0 * p0a.z + w1 * p1a.z + w2 * p2a.z;
      float e3 = w0 * p0a.w + w1 * p1a.w + w2 * p2a.w;
      float e4 = w0 * p0b.x + w1 * p1b.x + w2 * p2b.x;
      float e5 = w0 * p0b.y + w1 * p1b.y + w2 * p2b.y;
      float e6 = w0 * p0b.z + w1 * p1b.z + w2 * p2b.z;
      float e7 = w0 * p0b.w + w1 * p1b.w + w2 * p2b.w;
      uint4 packed;
      packed.x = pk2bf(e0, e1); packed.y = pk2bf(e2, e3);
      packed.z = pk2bf(e4, e5); packed.w = pk2bf(e6, e7);
      *(uint4*)&Fs[((kt * 4 + wv) * 64 + lane) * 8] = packed;
    }
#pragma unroll 2
    for (int kt = 8; kt < 12; ++kt) {  // unknow_feats region (C1 channels)
      int c1 = (kt - 8) * 32 + quad * 8;
      float e[8];
#pragma unroll
      for (int j = 0; j < 8; ++j)
        e[j] = uf[((size_t)b * C1 + c1 + j) * Nn + n];
      uint4 packed;
      packed.x = pk2bf(e[0], e[1]); packed.y = pk2bf(e[2], e[3]);
      packed.z = pk2bf(e[4], e[5]); packed.w = pk2bf(e[6], e[7]);
      *(uint4*)&Fs[((kt * 4 + wv) * 64 + lane) * 8] = packed;
    }
  }
  __syncthreads();  // barrier 1: Fs ready

  // ---- K-loop 1: wave wv owns rows wv*64..+63 (4 row-tiles) x 4 col-tiles
  f32x4 acc[4][4];
#pragma unroll
  for (int r = 0; r < 4; ++r)
#pragma unroll
    for (int c = 0; c < 4; ++c) acc[r][c] = (f32x4){0.f, 0.f, 0.f, 0.f};

  for (int kt = 0; kt < KT1; ++kt) {
    bf16x8 Afr[4], Bfr[4];
#pragma unroll
    for (int r = 0; r < 4; ++r)
      Afr[r] = *(const bf16x8*)(W1f + ((size_t)(kt * RT + wv * 4 + r) * 64 + lane) * 8);
#pragma unroll
    for (int c = 0; c < 4; ++c)
      Bfr[c] = *(const bf16x8*)&Fs[((kt * 4 + c) * 64 + lane) * 8];
#pragma unroll
    for (int r = 0; r < 4; ++r)
#pragma unroll
      for (int c = 0; c < 4; ++c)
        acc[r][c] = __builtin_amdgcn_mfma_f32_16x16x32_bf16(Afr[r], Bfr[c], acc[r][c], 0, 0, 0);
  }
  __syncthreads();  // barrier 2: all Fs reads done; Hs may overwrite Fs head

  // ---- Epilogue 1: bias+relu in D-layout, then register bpermute D->B-frag.
#pragma unroll
  for (int r = 0; r < 4; ++r) {
    f32x4 bq = *(const f32x4*)&b1[wv * 64 + r * 16 + quad * 4];
#pragma unroll
    for (int c = 0; c < 4; ++c)
#pragma unroll
      for (int reg = 0; reg < 4; ++reg)
        acc[r][c][reg] = fmaxf(acc[r][c][reg] + bq[reg], 0.f);
  }
  {
    int addr_lo = (((quad & 1) * 2) * 16 + col) * 4;  // src lane*4 for j<4
    bool hiSel = lane >= 32;
#pragma unroll
    for (int ktl = 0; ktl < 2; ++ktl)
#pragma unroll
      for (int c = 0; c < 4; ++c) {
        float e[8];
#pragma unroll
        for (int j = 0; j < 8; ++j) {
          int addr = addr_lo + (j >> 2) * 64;
          int lo = __builtin_amdgcn_ds_bpermute(addr, __float_as_int(acc[ktl * 2][c][j & 3]));
          int hi = __builtin_amdgcn_ds_bpermute(addr, __float_as_int(acc[ktl * 2 + 1][c][j & 3]));
          e[j] = __int_as_float(hiSel ? hi : lo);
        }
        uint4 packed;
        packed.x = pk2bf(e[0], e[1]); packed.y = pk2bf(e[2], e[3]);
        packed.z = pk2bf(e[4], e[5]); packed.w = pk2bf(e[6], e[7]);
        *(uint4*)&Hs[(((wv * 2 + ktl) * 4 + c) * 64 + lane) * 8] = packed;
      }
  }
  __syncthreads();  // barrier 3: Hs ready

  // ---- K-loop 2
  f32x4 acc2[4][4];
#pragma unroll
  for (int r = 0; r < 4; ++r)
#pragma unroll
    for (int c = 0; c < 4; ++c) acc2[r][c] = (f32x4){0.f, 0.f, 0.f, 0.f};

  for (int kt = 0; kt < KT2; ++kt) {
    bf16x8 Afr[4], Bfr[4];
#pragma unroll
    for (int r = 0; r < 4; ++r)
      Afr[r] = *(const bf16x8*)(W2f + ((size_t)(kt * RT + wv * 4 + r) * 64 + lane) * 8);
#pragma unroll
    for (int c = 0; c < 4; ++c)
      Bfr[c] = *(const bf16x8*)&Hs[((kt * 4 + c) * 64 + lane) * 8];
#pragma unroll
    for (int r = 0; r < 4; ++r)
#pragma unroll
      for (int c = 0; c < 4; ++c)
        acc2[r][c] = __builtin_amdgcn_mfma_f32_16x16x32_bf16(Afr[r], Bfr[c], acc2[r][c], 0, 0, 0);
  }

  // ---- Epilogue 2: bias+relu, store
#pragma unroll
  for (int r = 0; r < 4; ++r) {
    f32x4 bq = *(const f32x4*)&b2[wv * 64 + r * 16 + quad * 4];
#pragma unroll
    for (int c = 0; c < 4; ++c)
#pragma unroll
      for (int reg = 0; reg < 4; ++reg) {
        int rowg = wv * 64 + r * 16 + quad * 4 + reg;
        int n = bt * 64 + c * 16 + col;
        out[((size_t)b * Hh + rowg) * Nn + n] = fmaxf(acc2[r][c][reg] + bq[reg], 0.f);
      }
  }
}

extern "C" void kernel_launch(void* const* d_in, const int* in_sizes, int n_in,
                              void* d_out, int out_size, void* d_ws, size_t ws_size,
                              hipStream_t stream) {
  const float* unknown = (const float*)d_in[0];
  const float* known   = (const float*)d_in[1];
  const float* uf      = (const float*)d_in[2];
  const float* kf      = (const float*)d_in[3];
  const float* W1      = (const float*)d_in[4];
  const float* b1      = (const float*)d_in[5];
  const float* W2      = (const float*)d_in[6];
  const float* b2      = (const float*)d_in[7];
  float* out = (float*)d_out;

  // ws layout (~24 MB)
  char* p = (char*)d_ws;
  float* kfT = (float*)p;  p += (size_t)Bb * Mm * C2 * 4;
  short* W1f = (short*)p;  p += (size_t)KT1 * RT * 64 * 8 * 2;
  short* W2f = (short*)p;  p += (size_t)KT2 * RT * 64 * 8 * 2;
  float* pd  = (float*)p;  p += (size_t)Bb * Nn * NQ * 3 * 4;
  int* pi    = (int*)p;    p += (size_t)Bb * Nn * NQ * 3 * 4;

  prep_nn_k<<<dim3(NN_BASE + NN_BLOCKS), dim3(256), 0, stream>>>(
      kf, kfT, W1, W2, W1f, W2f, unknown, known, pd, pi);
  fused_gemm_k<<<dim3(Bb * (Nn / 64)), dim3(256), 0, stream>>>(
      uf, kfT, W1f, b1, W2f, b2, pd, pi, out);
}

// Round 7
// 230.203 us; speedup vs baseline: 1.1199x; 1.1199x over previous
//
#include <hip/hip_runtime.h>

using bf16x8 = __attribute__((ext_vector_type(8))) short;
using f32x4  = __attribute__((ext_vector_type(4))) float;

constexpr int Bb = 8, Nn = 8192, Mm = 2048, C1 = 128, C2 = 256, Hh = 256, K1 = 384;
constexpr int KT1 = K1 / 32;   // 12 k-tiles for GEMM1
constexpr int KT2 = Hh / 32;   // 8 k-tiles for GEMM2
constexpr int RT = Hh / 16;    // 16 row-tiles
constexpr int NQ = 4;          // candidate-set split for three_nn
constexpr int MQ = Mm / NQ;    // 512 candidates per quarter

__device__ __forceinline__ short f2bf(float x) {  // RNE float->bf16
  union { float f; unsigned u; } v; v.f = x;
  unsigned r = v.u + 0x7fff + ((v.u >> 16) & 1);
  return (short)(r >> 16);
}

// packed RNE float2 -> 2x bf16 in one dword (hw instr when available)
__device__ __forceinline__ unsigned pk2bf(float a, float b) {
#if defined(__has_builtin) && __has_builtin(__builtin_amdgcn_cvt_pk_bf16_f32)
  typedef __attribute__((ext_vector_type(2))) __bf16 bf2_t;
  bf2_t r = __builtin_amdgcn_cvt_pk_bf16_f32(a, b);
  union { bf2_t v; unsigned u; } cvt; cvt.v = r;
  return cvt.u;
#else
  return (unsigned)(unsigned short)f2bf(a) | ((unsigned)(unsigned short)f2bf(b) << 16);
#endif
}

// stable 2-list merge of sorted triples; ties prefer list a (lower global idx)
__device__ __forceinline__ void merge3(float a0, float a1, float a2, int A0, int A1, int A2,
                                       float b0, float b1, float b2, int B0, int B1, int B2,
                                       float& m0, float& m1, float& m2,
                                       int& j0, int& j1, int& j2) {
  bool ta = a0 <= b0;
  m0 = ta ? a0 : b0; j0 = ta ? A0 : B0;
  float na0 = ta ? a1 : a0, na1 = ta ? a2 : a1;
  int   nA0 = ta ? A1 : A0, nA1 = ta ? A2 : A1;
  float nb0 = ta ? b0 : b1, nb1 = ta ? b1 : b2;
  int   nB0 = ta ? B0 : B1, nB1 = ta ? B1 : B2;
  ta = na0 <= nb0;
  m1 = ta ? na0 : nb0; j1 = ta ? nA0 : nB0;
  float ma0 = ta ? na1 : na0; int mA0 = ta ? nA1 : nA0;
  float mb0 = ta ? nb0 : nb1; int mB0 = ta ? nB0 : nB1;
  ta = ma0 <= mb0;
  m2 = ta ? ma0 : mb0; j2 = ta ? mA0 : mB0;
}

// ------------- prep: kf transpose (blocks 0..4095) + W frag prep -------------
// NOTE: prep and nn are SEPARATE kernels. R5/R6 fused them into one grid and the
// 4096 transpose blocks dispatched ahead of the nn blocks, staggering/serializing
// the nn phase (+40 us). Launch overhead is fixed (~85 us regardless of 2/3/6
// launches), so kernel-count reduction has no value — do not re-fuse.
__global__ __launch_bounds__(256) void prep_all_k(const float* __restrict__ kf,
                                                  float* __restrict__ kfT,
                                                  const float* __restrict__ W1,
                                                  const float* __restrict__ W2,
                                                  short* __restrict__ W1f,
                                                  short* __restrict__ W2f) {
  __shared__ float tile[32][33];
  int bid = blockIdx.x, tid = threadIdx.x;
  if (bid < 4096) {  // transpose role: (B,C2,Mm) -> (B,Mm,C2)
    int cx = bid & 63, ry = (bid >> 6) & 7, z = bid >> 9;
    const int R = C2, C = Mm;
    const float* src = kf + (size_t)z * R * C;
    float* dst = kfT + (size_t)z * R * C;
    int c0 = cx * 32, r0 = ry * 32;
    int tx = tid & 31, ty = tid >> 5;
#pragma unroll
    for (int rr = ty; rr < 32; rr += 8) tile[rr][tx] = src[(size_t)(r0 + rr) * C + c0 + tx];
    __syncthreads();
#pragma unroll
    for (int cc = ty; cc < 32; cc += 8) dst[(size_t)(c0 + cc) * R + r0 + tx] = tile[tx][cc];
    return;
  }
  // W-prep role: A-frag planes (lane holds A[m=lane&15][k0..k0+7], k0=(lane>>4)*8)
  int id = (bid - 4096) * 256 + tid;
  const int n1 = KT1 * RT * 64;
  const int n2 = KT2 * RT * 64;
  if (id < n1) {
    int lane = id & 63, t = id >> 6;
    int kt = t / RT, rt = t % RT;
    int m = rt * 16 + (lane & 15), k0 = kt * 32 + (lane >> 4) * 8;
    bf16x8 f;
#pragma unroll
    for (int j = 0; j < 8; ++j) f[j] = f2bf(W1[(size_t)m * K1 + k0 + j]);
    *(bf16x8*)(W1f + (size_t)id * 8) = f;
  } else if (id < n1 + n2) {
    int id2 = id - n1;
    int lane = id2 & 63, t = id2 >> 6;
    int kt = t / RT, rt = t % RT;
    int m = rt * 16 + (lane & 15), k0 = kt * 32 + (lane >> 4) * 8;
    bf16x8 f;
#pragma unroll
    for (int j = 0; j < 8; ++j) f[j] = f2bf(W2[(size_t)m * Hh + k0 + j]);
    *(bf16x8*)(W2f + (size_t)id2 * 8) = f;
  }
}

// ------------- three_nn over a quarter of the candidate set (R4-verbatim) -------------
// grid: b(8) x nblk(32) x q(4) = 1024 blocks of 256 -> 16 waves/CU.
// Measured R4: 70 us, VALUBusy 79%. R5's scalar-load variant regressed (107 us,
// latency-bound) — LDS-staged broadcast is the right structure.
__global__ __launch_bounds__(256) void nn_quarter_k(const float* __restrict__ unknown,
                                                    const float* __restrict__ known,
                                                    float* __restrict__ pd,
                                                    int* __restrict__ pi) {
  __shared__ float kx[MQ], ky[MQ], kz[MQ];
  int bid = blockIdx.x;
  int b = bid >> 7, rem = bid & 127;
  int q = rem & 3, nblk = rem >> 2;
  int n = nblk * 256 + threadIdx.x;
  const float* kb = known + ((size_t)b * Mm + q * MQ) * 3;
  for (int p = threadIdx.x; p < MQ; p += 256) {
    kx[p] = kb[3 * p]; ky[p] = kb[3 * p + 1]; kz[p] = kb[3 * p + 2];
  }
  __syncthreads();

  size_t ui = ((size_t)b * Nn + n) * 3;
  float ux = unknown[ui], uy = unknown[ui + 1], uz = unknown[ui + 2];
  float d0 = 1e30f, d1 = 1e30f, d2 = 1e30f;
  int i0 = 0, i1 = 0, i2 = 0;
  int gbase = q * MQ;

#define NN_STEP(xx, yy, zz, qq)                                         \
  {                                                                     \
    float dx = ux - (xx), dy = uy - (yy), dz = uz - (zz);               \
    float dd = dx * dx + dy * dy + dz * dz;                             \
    if (__any(dd < d2)) {  /* wave-uniform skip of the insert chain */  \
      int jm = gbase + jb + (qq);                                       \
      bool c0 = dd < d0, c1 = dd < d1, c2 = dd < d2;                    \
      d2 = c1 ? d1 : (c2 ? dd : d2); i2 = c1 ? i1 : (c2 ? jm : i2);     \
      d1 = c0 ? d0 : (c1 ? dd : d1); i1 = c0 ? i0 : (c1 ? jm : i1);     \
      d0 = c0 ? dd : d0;             i0 = c0 ? jm : i0;                 \
    }                                                                   \
  }

  for (int jb = 0; jb < MQ; jb += 4) {
    float4 xs = *(const float4*)&kx[jb];
    float4 ys = *(const float4*)&ky[jb];
    float4 zs = *(const float4*)&kz[jb];
    NN_STEP(xs.x, ys.x, zs.x, 0)
    NN_STEP(xs.y, ys.y, zs.y, 1)
    NN_STEP(xs.z, ys.z, zs.z, 2)
    NN_STEP(xs.w, ys.w, zs.w, 3)
  }
#undef NN_STEP

  size_t o = (((size_t)b * Nn + n) * NQ + q) * 3;
  pd[o] = d0; pd[o + 1] = d1; pd[o + 2] = d2;
  pi[o] = i0; pi[o + 1] = i1; pi[o + 2] = i2;
}

// ------------- fused: 4-way merge -> gather+concat -> MLP1 -> MLP2 -> out -------------
// block = 256 thr (4 waves), 64 cols x 256 rows. grid = 8*128 = 1024.
// LDS: 48KB total — Hs ALIASES the head of Fs (barrier between K-loop1 reads and
// Hs writes makes this safe) -> 3 blocks/CU.
__global__ __launch_bounds__(256) void fused_gemm_k(
    const float* __restrict__ uf, const float* __restrict__ kfT,
    const short* __restrict__ W1f, const float* __restrict__ b1,
    const short* __restrict__ W2f, const float* __restrict__ b2,
    const float* __restrict__ pd, const int* __restrict__ pi,
    float* __restrict__ out) {
  __shared__ short Fs[KT1 * 4 * 64 * 8];  // B-frags of F [kt][ntl][lane][j]; head reused as Hs
  short* Hs = Fs;                         // B-frags of h (16384 shorts)
  int bid = blockIdx.x;
  int b = bid >> 7, bt = bid & 127;  // n0 = bt*64
  int tid = threadIdx.x, lane = tid & 63, wv = tid >> 6;
  int quad = lane >> 4, col = lane & 15;

  // ---- Phase A: in-register 4-way NN merge, then gather+concat F in B-frag layout
  {
    int n = bt * 64 + wv * 16 + col;
    size_t pbase = (size_t)(b * Nn + n) * (NQ * 3);
    float4 da = *(const float4*)&pd[pbase];
    float4 db = *(const float4*)&pd[pbase + 4];
    float4 dc = *(const float4*)&pd[pbase + 8];
    int4 ia = *(const int4*)&pi[pbase];
    int4 ib = *(const int4*)&pi[pbase + 4];
    int4 ic = *(const int4*)&pi[pbase + 8];
    float t0, t1, t2, u0, u1, u2, m0, m1, m2;
    int T0, T1, T2, U0, U1, U2, g0, g1, g2;
    merge3(da.x, da.y, da.z, ia.x, ia.y, ia.z,
           da.w, db.x, db.y, ia.w, ib.x, ib.y, t0, t1, t2, T0, T1, T2);
    merge3(db.z, db.w, dc.x, ib.z, ib.w, ic.x,
           dc.y, dc.z, dc.w, ic.y, ic.z, ic.w, u0, u1, u2, U0, U1, U2);
    merge3(t0, t1, t2, T0, T1, T2, u0, u1, u2, U0, U1, U2,
           m0, m1, m2, g0, g1, g2);
    float s0 = sqrtf(m0), s1 = sqrtf(m1), s2 = sqrtf(m2);
    float r0 = 1.f / (s0 + 1e-8f), r1 = 1.f / (s1 + 1e-8f), r2 = 1.f / (s2 + 1e-8f);
    float rs = 1.f / (r0 + r1 + r2);
    float w0 = r0 * rs, w1 = r1 * rs, w2 = r2 * rs;

    const float* kfb = kfT + (size_t)b * Mm * C2;
#pragma unroll 4
    for (int kt = 0; kt < 8; ++kt) {  // interpolated region (C2 channels)
      int c0 = kt * 32 + quad * 8;
      float4 p0a = *(const float4*)&kfb[(size_t)g0 * C2 + c0];
      float4 p0b = *(const float4*)&kfb[(size_t)g0 * C2 + c0 + 4];
      float4 p1a = *(const float4*)&kfb[(size_t)g1 * C2 + c0];
      float4 p1b = *(const float4*)&kfb[(size_t)g1 * C2 + c0 + 4];
      float4 p2a = *(const float4*)&kfb[(size_t)g2 * C2 + c0];
      float4 p2b = *(const float4*)&kfb[(size_t)g2 * C2 + c0 + 4];
      float e0 = w0 * p0a.x + w1 * p1a.x + w2 * p2a.x;
      float e1 = w0 * p0a.y + w1 * p1a.y + w2 * p2a.y;
      float e2 = w0 * p0a.z + w1 * p1a.z + w2 * p2a.z;
      float e3 = w0 * p0a.w + w1 * p1a.w + w2 * p2a.w;
      float e4 = w0 * p0b.x + w1 * p1b.x + w2 * p2b.x;
      float e5 = w0 * p0b.y + w1 * p1b.y + w2 * p2b.y;
      float e6 = w0 * p0b.z + w1 * p1b.z + w2 * p2b.z;
      float e7 = w0 * p0b.w + w1 * p1b.w + w2 * p2b.w;
      uint4 packed;
      packed.x = pk2bf(e0, e1); packed.y = pk2bf(e2, e3);
      packed.z = pk2bf(e4, e5); packed.w = pk2bf(e6, e7);
      *(uint4*)&Fs[((kt * 4 + wv) * 64 + lane) * 8] = packed;
    }
#pragma unroll 2
    for (int kt = 8; kt < 12; ++kt) {  // unknow_feats region (C1 channels)
      int c1 = (kt - 8) * 32 + quad * 8;
      float e[8];
#pragma unroll
      for (int j = 0; j < 8; ++j)
        e[j] = uf[((size_t)b * C1 + c1 + j) * Nn + n];
      uint4 packed;
      packed.x = pk2bf(e[0], e[1]); packed.y = pk2bf(e[2], e[3]);
      packed.z = pk2bf(e[4], e[5]); packed.w = pk2bf(e[6], e[7]);
      *(uint4*)&Fs[((kt * 4 + wv) * 64 + lane) * 8] = packed;
    }
  }
  __syncthreads();  // barrier 1: Fs ready

  // ---- K-loop 1: wave wv owns rows wv*64..+63 (4 row-tiles) x 4 col-tiles
  f32x4 acc[4][4];
#pragma unroll
  for (int r = 0; r < 4; ++r)
#pragma unroll
    for (int c = 0; c < 4; ++c) acc[r][c] = (f32x4){0.f, 0.f, 0.f, 0.f};

  for (int kt = 0; kt < KT1; ++kt) {
    bf16x8 Afr[4], Bfr[4];
#pragma unroll
    for (int r = 0; r < 4; ++r)
      Afr[r] = *(const bf16x8*)(W1f + ((size_t)(kt * RT + wv * 4 + r) * 64 + lane) * 8);
#pragma unroll
    for (int c = 0; c < 4; ++c)
      Bfr[c] = *(const bf16x8*)&Fs[((kt * 4 + c) * 64 + lane) * 8];
#pragma unroll
    for (int r = 0; r < 4; ++r)
#pragma unroll
      for (int c = 0; c < 4; ++c)
        acc[r][c] = __builtin_amdgcn_mfma_f32_16x16x32_bf16(Afr[r], Bfr[c], acc[r][c], 0, 0, 0);
  }
  __syncthreads();  // barrier 2: all Fs reads done; Hs may overwrite Fs head

  // ---- Epilogue 1: bias+relu in D-layout, then register bpermute D->B-frag.
#pragma unroll
  for (int r = 0; r < 4; ++r) {
    f32x4 bq = *(const f32x4*)&b1[wv * 64 + r * 16 + quad * 4];
#pragma unroll
    for (int c = 0; c < 4; ++c)
#pragma unroll
      for (int reg = 0; reg < 4; ++reg)
        acc[r][c][reg] = fmaxf(acc[r][c][reg] + bq[reg], 0.f);
  }
  {
    int addr_lo = (((quad & 1) * 2) * 16 + col) * 4;  // src lane*4 for j<4
    bool hiSel = lane >= 32;
#pragma unroll
    for (int ktl = 0; ktl < 2; ++ktl)
#pragma unroll
      for (int c = 0; c < 4; ++c) {
        float e[8];
#pragma unroll
        for (int j = 0; j < 8; ++j) {
          int addr = addr_lo + (j >> 2) * 64;
          int lo = __builtin_amdgcn_ds_bpermute(addr, __float_as_int(acc[ktl * 2][c][j & 3]));
          int hi = __builtin_amdgcn_ds_bpermute(addr, __float_as_int(acc[ktl * 2 + 1][c][j & 3]));
          e[j] = __int_as_float(hiSel ? hi : lo);
        }
        uint4 packed;
        packed.x = pk2bf(e[0], e[1]); packed.y = pk2bf(e[2], e[3]);
        packed.z = pk2bf(e[4], e[5]); packed.w = pk2bf(e[6], e[7]);
        *(uint4*)&Hs[(((wv * 2 + ktl) * 4 + c) * 64 + lane) * 8] = packed;
      }
  }
  __syncthreads();  // barrier 3: Hs ready

  // ---- K-loop 2
  f32x4 acc2[4][4];
#pragma unroll
  for (int r = 0; r < 4; ++r)
#pragma unroll
    for (int c = 0; c < 4; ++c) acc2[r][c] = (f32x4){0.f, 0.f, 0.f, 0.f};

  for (int kt = 0; kt < KT2; ++kt) {
    bf16x8 Afr[4], Bfr[4];
#pragma unroll
    for (int r = 0; r < 4; ++r)
      Afr[r] = *(const bf16x8*)(W2f + ((size_t)(kt * RT + wv * 4 + r) * 64 + lane) * 8);
#pragma unroll
    for (int c = 0; c < 4; ++c)
      Bfr[c] = *(const bf16x8*)&Hs[((kt * 4 + c) * 64 + lane) * 8];
#pragma unroll
    for (int r = 0; r < 4; ++r)
#pragma unroll
      for (int c = 0; c < 4; ++c)
        acc2[r][c] = __builtin_amdgcn_mfma_f32_16x16x32_bf16(Afr[r], Bfr[c], acc2[r][c], 0, 0, 0);
  }

  // ---- Epilogue 2: bias+relu, store
#pragma unroll
  for (int r = 0; r < 4; ++r) {
    f32x4 bq = *(const f32x4*)&b2[wv * 64 + r * 16 + quad * 4];
#pragma unroll
    for (int c = 0; c < 4; ++c)
#pragma unroll
      for (int reg = 0; reg < 4; ++reg) {
        int rowg = wv * 64 + r * 16 + quad * 4 + reg;
        int n = bt * 64 + c * 16 + col;
        out[((size_t)b * Hh + rowg) * Nn + n] = fmaxf(acc2[r][c][reg] + bq[reg], 0.f);
      }
  }
}

extern "C" void kernel_launch(void* const* d_in, const int* in_sizes, int n_in,
                              void* d_out, int out_size, void* d_ws, size_t ws_size,
                              hipStream_t stream) {
  const float* unknown = (const float*)d_in[0];
  const float* known   = (const float*)d_in[1];
  const float* uf      = (const float*)d_in[2];
  const float* kf      = (const float*)d_in[3];
  const float* W1      = (const float*)d_in[4];
  const float* b1      = (const float*)d_in[5];
  const float* W2      = (const float*)d_in[6];
  const float* b2      = (const float*)d_in[7];
  float* out = (float*)d_out;

  // ws layout (~24 MB)
  char* p = (char*)d_ws;
  float* kfT = (float*)p;  p += (size_t)Bb * Mm * C2 * 4;
  short* W1f = (short*)p;  p += (size_t)KT1 * RT * 64 * 8 * 2;
  short* W2f = (short*)p;  p += (size_t)KT2 * RT * 64 * 8 * 2;
  float* pd  = (float*)p;  p += (size_t)Bb * Nn * NQ * 3 * 4;
  int* pi    = (int*)p;    p += (size_t)Bb * Nn * NQ * 3 * 4;

  const int prep_blocks = 4096 + (KT1 * RT * 64 + KT2 * RT * 64 + 255) / 256;
  prep_all_k<<<dim3(prep_blocks), dim3(256), 0, stream>>>(kf, kfT, W1, W2, W1f, W2f);
  nn_quarter_k<<<dim3(Bb * 32 * NQ), dim3(256), 0, stream>>>(unknown, known, pd, pi);
  fused_gemm_k<<<dim3(Bb * (Nn / 64)), dim3(256), 0, stream>>>(
      uf, kfT, W1f, b1, W2f, b2, pd, pi, out);
}

// Round 8
// 221.478 us; speedup vs baseline: 1.1641x; 1.0394x over previous
//
#include <hip/hip_runtime.h>

using bf16x8 = __attribute__((ext_vector_type(8))) short;
using f32x4  = __attribute__((ext_vector_type(4))) float;

constexpr int Bb = 8, Nn = 8192, Mm = 2048, C1 = 128, C2 = 256, Hh = 256, K1 = 384;
constexpr int KT1 = K1 / 32;   // 12 k-tiles for GEMM1
constexpr int KT2 = Hh / 32;   // 8 k-tiles for GEMM2
constexpr int RT = Hh / 16;    // 16 row-tiles
constexpr int NQ = 4;          // candidate-set split for three_nn
constexpr int MQ = Mm / NQ;    // 512 candidates per quarter

__device__ __forceinline__ short f2bf(float x) {  // RNE float->bf16
  union { float f; unsigned u; } v; v.f = x;
  unsigned r = v.u + 0x7fff + ((v.u >> 16) & 1);
  return (short)(r >> 16);
}

// packed RNE float2 -> 2x bf16 in one dword (hw instr when available)
__device__ __forceinline__ unsigned pk2bf(float a, float b) {
#if defined(__has_builtin) && __has_builtin(__builtin_amdgcn_cvt_pk_bf16_f32)
  typedef __attribute__((ext_vector_type(2))) __bf16 bf2_t;
  bf2_t r = __builtin_amdgcn_cvt_pk_bf16_f32(a, b);
  union { bf2_t v; unsigned u; } cvt; cvt.v = r;
  return cvt.u;
#else
  return (unsigned)(unsigned short)f2bf(a) | ((unsigned)(unsigned short)f2bf(b) << 16);
#endif
}

// unpack a dword holding 2 bf16 (lo = element 2i, hi = element 2i+1)
__device__ __forceinline__ float bflo(unsigned d) { return __uint_as_float(d << 16); }
__device__ __forceinline__ float bfhi(unsigned d) { return __uint_as_float(d & 0xffff0000u); }

// stable 2-list merge of sorted triples; ties prefer list a (lower global idx)
__device__ __forceinline__ void merge3(float a0, float a1, float a2, int A0, int A1, int A2,
                                       float b0, float b1, float b2, int B0, int B1, int B2,
                                       float& m0, float& m1, float& m2,
                                       int& j0, int& j1, int& j2) {
  bool ta = a0 <= b0;
  m0 = ta ? a0 : b0; j0 = ta ? A0 : B0;
  float na0 = ta ? a1 : a0, na1 = ta ? a2 : a1;
  int   nA0 = ta ? A1 : A0, nA1 = ta ? A2 : A1;
  float nb0 = ta ? b0 : b1, nb1 = ta ? b1 : b2;
  int   nB0 = ta ? B0 : B1, nB1 = ta ? B1 : B2;
  ta = na0 <= nb0;
  m1 = ta ? na0 : nb0; j1 = ta ? nA0 : nB0;
  float ma0 = ta ? na1 : na0; int mA0 = ta ? nA1 : nA0;
  float mb0 = ta ? nb0 : nb1; int mB0 = ta ? nB0 : nB1;
  ta = ma0 <= mb0;
  m2 = ta ? ma0 : mb0; j2 = ta ? mA0 : mB0;
}

// ------------- prep: kf transpose->bf16 (blocks 0..4095) + W frag prep -------------
// NOTE: prep, nn, fused stay SEPARATE kernels (R5/R6: fusing roles into one grid
// serialized the nn phase behind the transpose blocks, +40 us; launch overhead is
// fixed ~85 us regardless of kernel count — do not re-fuse).
__global__ __launch_bounds__(256) void prep_all_k(const float* __restrict__ kf,
                                                  short* __restrict__ kfTb,
                                                  const float* __restrict__ W1,
                                                  const float* __restrict__ W2,
                                                  short* __restrict__ W1f,
                                                  short* __restrict__ W2f) {
  __shared__ float tile[32][33];
  int bid = blockIdx.x, tid = threadIdx.x;
  if (bid < 4096) {  // transpose role: (B,C2,Mm) f32 -> (B,Mm,C2) bf16
    int cx = bid & 63, ry = (bid >> 6) & 7, z = bid >> 9;
    const float* src = kf + (size_t)z * C2 * Mm;
    short* dst = kfTb + (size_t)z * Mm * C2;
    int c0 = cx * 32, r0 = ry * 32;  // c0: point base, r0: channel base
    int tx = tid & 31, ty = tid >> 5;
#pragma unroll
    for (int rr = ty; rr < 32; rr += 8)
      tile[rr][tx] = src[(size_t)(r0 + rr) * Mm + c0 + tx];
    __syncthreads();
#pragma unroll
    for (int cc = ty; cc < 32; cc += 8)
      dst[(size_t)(c0 + cc) * C2 + r0 + tx] = f2bf(tile[tx][cc]);
    return;
  }
  // W-prep role: A-frag planes (lane holds A[m=lane&15][k0..k0+7], k0=(lane>>4)*8)
  int id = (bid - 4096) * 256 + tid;
  const int n1 = KT1 * RT * 64;
  const int n2 = KT2 * RT * 64;
  if (id < n1) {
    int lane = id & 63, t = id >> 6;
    int kt = t / RT, rt = t % RT;
    int m = rt * 16 + (lane & 15), k0 = kt * 32 + (lane >> 4) * 8;
    bf16x8 f;
#pragma unroll
    for (int j = 0; j < 8; ++j) f[j] = f2bf(W1[(size_t)m * K1 + k0 + j]);
    *(bf16x8*)(W1f + (size_t)id * 8) = f;
  } else if (id < n1 + n2) {
    int id2 = id - n1;
    int lane = id2 & 63, t = id2 >> 6;
    int kt = t / RT, rt = t % RT;
    int m = rt * 16 + (lane & 15), k0 = kt * 32 + (lane >> 4) * 8;
    bf16x8 f;
#pragma unroll
    for (int j = 0; j < 8; ++j) f[j] = f2bf(W2[(size_t)m * Hh + k0 + j]);
    *(bf16x8*)(W2f + (size_t)id2 * 8) = f;
  }
}

// ------------- three_nn over a quarter of the candidate set (R4-verbatim) -------------
// grid: b(8) x nblk(32) x q(4) = 1024 blocks of 256 -> 16 waves/CU.
// Measured: 68.5 us, VALUBusy 82%. R5's scalar-load variant regressed (107 us,
// latency-bound) — LDS-staged broadcast is the right structure.
__global__ __launch_bounds__(256) void nn_quarter_k(const float* __restrict__ unknown,
                                                    const float* __restrict__ known,
                                                    float* __restrict__ pd,
                                                    int* __restrict__ pi) {
  __shared__ float kx[MQ], ky[MQ], kz[MQ];
  int bid = blockIdx.x;
  int b = bid >> 7, rem = bid & 127;
  int q = rem & 3, nblk = rem >> 2;
  int n = nblk * 256 + threadIdx.x;
  const float* kb = known + ((size_t)b * Mm + q * MQ) * 3;
  for (int p = threadIdx.x; p < MQ; p += 256) {
    kx[p] = kb[3 * p]; ky[p] = kb[3 * p + 1]; kz[p] = kb[3 * p + 2];
  }
  __syncthreads();

  size_t ui = ((size_t)b * Nn + n) * 3;
  float ux = unknown[ui], uy = unknown[ui + 1], uz = unknown[ui + 2];
  float d0 = 1e30f, d1 = 1e30f, d2 = 1e30f;
  int i0 = 0, i1 = 0, i2 = 0;
  int gbase = q * MQ;

#define NN_STEP(xx, yy, zz, qq)                                         \
  {                                                                     \
    float dx = ux - (xx), dy = uy - (yy), dz = uz - (zz);               \
    float dd = dx * dx + dy * dy + dz * dz;                             \
    if (__any(dd < d2)) {  /* wave-uniform skip of the insert chain */  \
      int jm = gbase + jb + (qq);                                       \
      bool c0 = dd < d0, c1 = dd < d1, c2 = dd < d2;                    \
      d2 = c1 ? d1 : (c2 ? dd : d2); i2 = c1 ? i1 : (c2 ? jm : i2);     \
      d1 = c0 ? d0 : (c1 ? dd : d1); i1 = c0 ? i0 : (c1 ? jm : i1);     \
      d0 = c0 ? dd : d0;             i0 = c0 ? jm : i0;                 \
    }                                                                   \
  }

  for (int jb = 0; jb < MQ; jb += 4) {
    float4 xs = *(const float4*)&kx[jb];
    float4 ys = *(const float4*)&ky[jb];
    float4 zs = *(const float4*)&kz[jb];
    NN_STEP(xs.x, ys.x, zs.x, 0)
    NN_STEP(xs.y, ys.y, zs.y, 1)
    NN_STEP(xs.z, ys.z, zs.z, 2)
    NN_STEP(xs.w, ys.w, zs.w, 3)
  }
#undef NN_STEP

  size_t o = (((size_t)b * Nn + n) * NQ + q) * 3;
  pd[o] = d0; pd[o + 1] = d1; pd[o + 2] = d2;
  pi[o] = i0; pi[o + 1] = i1; pi[o + 2] = i2;
}

// ------------- fused: 4-way merge -> gather+concat -> MLP1 -> MLP2 -> out -------------
// block = 256 thr (4 waves), 64 cols x 256 rows. grid = 8*128 = 1024.
// LDS: 48KB — Hs aliases the head of Fs (barrier-separated) -> 3 blocks/CU.
// Gather is bf16 (24 x 16B loads/thread vs 48 in fp32): halves bytes + lines.
__global__ __launch_bounds__(256) void fused_gemm_k(
    const float* __restrict__ uf, const short* __restrict__ kfTb,
    const short* __restrict__ W1f, const float* __restrict__ b1,
    const short* __restrict__ W2f, const float* __restrict__ b2,
    const float* __restrict__ pd, const int* __restrict__ pi,
    float* __restrict__ out) {
  __shared__ short Fs[KT1 * 4 * 64 * 8];  // B-frags of F [kt][ntl][lane][j]; head reused as Hs
  short* Hs = Fs;                         // B-frags of h (16384 shorts)
  int bid = blockIdx.x;
  int b = bid >> 7, bt = bid & 127;  // n0 = bt*64
  int tid = threadIdx.x, lane = tid & 63, wv = tid >> 6;
  int quad = lane >> 4, col = lane & 15;

  // ---- Phase A: in-register 4-way NN merge, then gather+concat F in B-frag layout
  {
    int n = bt * 64 + wv * 16 + col;
    size_t pbase = (size_t)(b * Nn + n) * (NQ * 3);
    float4 da = *(const float4*)&pd[pbase];
    float4 db = *(const float4*)&pd[pbase + 4];
    float4 dc = *(const float4*)&pd[pbase + 8];
    int4 ia = *(const int4*)&pi[pbase];
    int4 ib = *(const int4*)&pi[pbase + 4];
    int4 ic = *(const int4*)&pi[pbase + 8];
    float t0, t1, t2, u0, u1, u2, m0, m1, m2;
    int T0, T1, T2, U0, U1, U2, g0, g1, g2;
    merge3(da.x, da.y, da.z, ia.x, ia.y, ia.z,
           da.w, db.x, db.y, ia.w, ib.x, ib.y, t0, t1, t2, T0, T1, T2);
    merge3(db.z, db.w, dc.x, ib.z, ib.w, ic.x,
           dc.y, dc.z, dc.w, ic.y, ic.z, ic.w, u0, u1, u2, U0, U1, U2);
    merge3(t0, t1, t2, T0, T1, T2, u0, u1, u2, U0, U1, U2,
           m0, m1, m2, g0, g1, g2);
    float s0 = sqrtf(m0), s1 = sqrtf(m1), s2 = sqrtf(m2);
    float r0 = 1.f / (s0 + 1e-8f), r1 = 1.f / (s1 + 1e-8f), r2 = 1.f / (s2 + 1e-8f);
    float rs = 1.f / (r0 + r1 + r2);
    float w0 = r0 * rs, w1 = r1 * rs, w2 = r2 * rs;

    const short* kfb = kfTb + (size_t)b * Mm * C2;
#pragma unroll 4
    for (int kt = 0; kt < 8; ++kt) {  // interpolated region (C2 channels), bf16 gather
      int c0 = kt * 32 + quad * 8;
      uint4 q0 = *(const uint4*)&kfb[(size_t)g0 * C2 + c0];
      uint4 q1 = *(const uint4*)&kfb[(size_t)g1 * C2 + c0];
      uint4 q2 = *(const uint4*)&kfb[(size_t)g2 * C2 + c0];
      float e0 = w0 * bflo(q0.x) + w1 * bflo(q1.x) + w2 * bflo(q2.x);
      float e1 = w0 * bfhi(q0.x) + w1 * bfhi(q1.x) + w2 * bfhi(q2.x);
      float e2 = w0 * bflo(q0.y) + w1 * bflo(q1.y) + w2 * bflo(q2.y);
      float e3 = w0 * bfhi(q0.y) + w1 * bfhi(q1.y) + w2 * bfhi(q2.y);
      float e4 = w0 * bflo(q0.z) + w1 * bflo(q1.z) + w2 * bflo(q2.z);
      float e5 = w0 * bfhi(q0.z) + w1 * bfhi(q1.z) + w2 * bfhi(q2.z);
      float e6 = w0 * bflo(q0.w) + w1 * bflo(q1.w) + w2 * bflo(q2.w);
      float e7 = w0 * bfhi(q0.w) + w1 * bfhi(q1.w) + w2 * bfhi(q2.w);
      uint4 packed;
      packed.x = pk2bf(e0, e1); packed.y = pk2bf(e2, e3);
      packed.z = pk2bf(e4, e5); packed.w = pk2bf(e6, e7);
      *(uint4*)&Fs[((kt * 4 + wv) * 64 + lane) * 8] = packed;
    }
#pragma unroll 2
    for (int kt = 8; kt < 12; ++kt) {  // unknow_feats region (C1 channels)
      int c1 = (kt - 8) * 32 + quad * 8;
      float e[8];
#pragma unroll
      for (int j = 0; j < 8; ++j)
        e[j] = uf[((size_t)b * C1 + c1 + j) * Nn + n];
      uint4 packed;
      packed.x = pk2bf(e[0], e[1]); packed.y = pk2bf(e[2], e[3]);
      packed.z = pk2bf(e[4], e[5]); packed.w = pk2bf(e[6], e[7]);
      *(uint4*)&Fs[((kt * 4 + wv) * 64 + lane) * 8] = packed;
    }
  }
  __syncthreads();  // barrier 1: Fs ready

  // ---- K-loop 1: wave wv owns rows wv*64..+63 (4 row-tiles) x 4 col-tiles
  f32x4 acc[4][4];
#pragma unroll
  for (int r = 0; r < 4; ++r)
#pragma unroll
    for (int c = 0; c < 4; ++c) acc[r][c] = (f32x4){0.f, 0.f, 0.f, 0.f};

  for (int kt = 0; kt < KT1; ++kt) {
    bf16x8 Afr[4], Bfr[4];
#pragma unroll
    for (int r = 0; r < 4; ++r)
      Afr[r] = *(const bf16x8*)(W1f + ((size_t)(kt * RT + wv * 4 + r) * 64 + lane) * 8);
#pragma unroll
    for (int c = 0; c < 4; ++c)
      Bfr[c] = *(const bf16x8*)&Fs[((kt * 4 + c) * 64 + lane) * 8];
#pragma unroll
    for (int r = 0; r < 4; ++r)
#pragma unroll
      for (int c = 0; c < 4; ++c)
        acc[r][c] = __builtin_amdgcn_mfma_f32_16x16x32_bf16(Afr[r], Bfr[c], acc[r][c], 0, 0, 0);
  }
  __syncthreads();  // barrier 2: all Fs reads done; Hs may overwrite Fs head

  // ---- Epilogue 1: bias+relu in D-layout, then register bpermute D->B-frag.
#pragma unroll
  for (int r = 0; r < 4; ++r) {
    f32x4 bq = *(const f32x4*)&b1[wv * 64 + r * 16 + quad * 4];
#pragma unroll
    for (int c = 0; c < 4; ++c)
#pragma unroll
      for (int reg = 0; reg < 4; ++reg)
        acc[r][c][reg] = fmaxf(acc[r][c][reg] + bq[reg], 0.f);
  }
  {
    int addr_lo = (((quad & 1) * 2) * 16 + col) * 4;  // src lane*4 for j<4
    bool hiSel = lane >= 32;
#pragma unroll
    for (int ktl = 0; ktl < 2; ++ktl)
#pragma unroll
      for (int c = 0; c < 4; ++c) {
        float e[8];
#pragma unroll
        for (int j = 0; j < 8; ++j) {
          int addr = addr_lo + (j >> 2) * 64;
          int lo = __builtin_amdgcn_ds_bpermute(addr, __float_as_int(acc[ktl * 2][c][j & 3]));
          int hi = __builtin_amdgcn_ds_bpermute(addr, __float_as_int(acc[ktl * 2 + 1][c][j & 3]));
          e[j] = __int_as_float(hiSel ? hi : lo);
        }
        uint4 packed;
        packed.x = pk2bf(e[0], e[1]); packed.y = pk2bf(e[2], e[3]);
        packed.z = pk2bf(e[4], e[5]); packed.w = pk2bf(e[6], e[7]);
        *(uint4*)&Hs[(((wv * 2 + ktl) * 4 + c) * 64 + lane) * 8] = packed;
      }
  }
  __syncthreads();  // barrier 3: Hs ready

  // ---- K-loop 2
  f32x4 acc2[4][4];
#pragma unroll
  for (int r = 0; r < 4; ++r)
#pragma unroll
    for (int c = 0; c < 4; ++c) acc2[r][c] = (f32x4){0.f, 0.f, 0.f, 0.f};

  for (int kt = 0; kt < KT2; ++kt) {
    bf16x8 Afr[4], Bfr[4];
#pragma unroll
    for (int r = 0; r < 4; ++r)
      Afr[r] = *(const bf16x8*)(W2f + ((size_t)(kt * RT + wv * 4 + r) * 64 + lane) * 8);
#pragma unroll
    for (int c = 0; c < 4; ++c)
      Bfr[c] = *(const bf16x8*)&Hs[((kt * 4 + c) * 64 + lane) * 8];
#pragma unroll
    for (int r = 0; r < 4; ++r)
#pragma unroll
      for (int c = 0; c < 4; ++c)
        acc2[r][c] = __builtin_amdgcn_mfma_f32_16x16x32_bf16(Afr[r], Bfr[c], acc2[r][c], 0, 0, 0);
  }

  // ---- Epilogue 2: bias+relu, store
#pragma unroll
  for (int r = 0; r < 4; ++r) {
    f32x4 bq = *(const f32x4*)&b2[wv * 64 + r * 16 + quad * 4];
#pragma unroll
    for (int c = 0; c < 4; ++c)
#pragma unroll
      for (int reg = 0; reg < 4; ++reg) {
        int rowg = wv * 64 + r * 16 + quad * 4 + reg;
        int n = bt * 64 + c * 16 + col;
        out[((size_t)b * Hh + rowg) * Nn + n] = fmaxf(acc2[r][c][reg] + bq[reg], 0.f);
      }
  }
}

extern "C" void kernel_launch(void* const* d_in, const int* in_sizes, int n_in,
                              void* d_out, int out_size, void* d_ws, size_t ws_size,
                              hipStream_t stream) {
  const float* unknown = (const float*)d_in[0];
  const float* known   = (const float*)d_in[1];
  const float* uf      = (const float*)d_in[2];
  const float* kf      = (const float*)d_in[3];
  const float* W1      = (const float*)d_in[4];
  const float* b1      = (const float*)d_in[5];
  const float* W2      = (const float*)d_in[6];
  const float* b2      = (const float*)d_in[7];
  float* out = (float*)d_out;

  // ws layout (~16 MB)
  char* p = (char*)d_ws;
  short* kfTb = (short*)p; p += (size_t)Bb * Mm * C2 * 2;   // 8.4 MB bf16
  short* W1f = (short*)p;  p += (size_t)KT1 * RT * 64 * 8 * 2;
  short* W2f = (short*)p;  p += (size_t)KT2 * RT * 64 * 8 * 2;
  float* pd  = (float*)p;  p += (size_t)Bb * Nn * NQ * 3 * 4;
  int* pi    = (int*)p;    p += (size_t)Bb * Nn * NQ * 3 * 4;

  const int prep_blocks = 4096 + (KT1 * RT * 64 + KT2 * RT * 64 + 255) / 256;
  prep_all_k<<<dim3(prep_blocks), dim3(256), 0, stream>>>(kf, kfTb, W1, W2, W1f, W2f);
  nn_quarter_k<<<dim3(Bb * 32 * NQ), dim3(256), 0, stream>>>(unknown, known, pd, pi);
  fused_gemm_k<<<dim3(Bb * (Nn / 64)), dim3(256), 0, stream>>>(
      uf, kfTb, W1f, b1, W2f, b2, pd, pi, out);
}